// Round 1
// baseline (172.653 us; speedup 1.0000x reference)
//
#include <hip/hip_runtime.h>
#include <hip/hip_bf16.h>

// GRU-D cell: B=16384, I=128, D=16.
// One thread per (b, i) block: loads 16 floats of h and gamma_h (4x float4),
// does three 16x16 mat-vecs with wave-uniform U matrices (scalar loads),
// applies sigmoid/tanh gating, writes 16 floats of out.
// Memory-bound: ~420 MB total traffic -> ~67 us floor at 6.3 TB/s.

constexpr int I_TOT = 128;
constexpr int D_DIM = 16;

__device__ __forceinline__ float fast_sigmoid(float x) {
    // exp(-x) -> inf for very negative x gives 1/(1+inf) = 0: safe, no NaN.
    return 1.0f / (1.0f + __expf(-x));
}

__device__ __forceinline__ float fast_tanh(float x) {
    // clamp to avoid inf/inf
    x = fminf(fmaxf(x, -10.0f), 10.0f);
    float e = __expf(-2.0f * x);
    return (1.0f - e) / (1.0f + e);
}

__global__ __launch_bounds__(256) void gru_d_cell(
    const float* __restrict__ h,
    const float* __restrict__ X,
    const float* __restrict__ M,
    const float* __restrict__ gamma_h,
    const float* __restrict__ W_r,
    const float* __restrict__ W_z,
    const float* __restrict__ W_h,
    const float* __restrict__ U_r,
    const float* __restrict__ U_z,
    const float* __restrict__ U_h,
    const float* __restrict__ V_r,
    const float* __restrict__ V_z,
    const float* __restrict__ V_h,
    const float* __restrict__ b_r,
    const float* __restrict__ b_z,
    const float* __restrict__ b_h,
    float* __restrict__ out)
{
    const int i = blockIdx.y;                        // wave-uniform feature index
    const int b = blockIdx.x * 256 + threadIdx.x;    // batch index

    // Wave-uniform parameter bases -> compiler should scalarize these loads.
    const float* __restrict__ Ur = U_r + i * (D_DIM * D_DIM);
    const float* __restrict__ Uz = U_z + i * (D_DIM * D_DIM);
    const float* __restrict__ Uh = U_h + i * (D_DIM * D_DIM);
    const float* __restrict__ Wr = W_r + i * D_DIM;
    const float* __restrict__ Wz = W_z + i * D_DIM;
    const float* __restrict__ Wh = W_h + i * D_DIM;
    const float* __restrict__ Vr = V_r + i * D_DIM;
    const float* __restrict__ Vz = V_z + i * D_DIM;
    const float* __restrict__ Vh = V_h + i * D_DIM;
    const float* __restrict__ br = b_r + i * D_DIM;
    const float* __restrict__ bz = b_z + i * D_DIM;
    const float* __restrict__ bh = b_h + i * D_DIM;

    const long base = (long)b * (I_TOT * D_DIM) + i * D_DIM;

    // hh = h * gamma_h  (decayed hidden state for this block)
    float hh[D_DIM];
    #pragma unroll
    for (int k = 0; k < 4; ++k) {
        float4 hv = *reinterpret_cast<const float4*>(h + base + 4 * k);
        float4 gv = *reinterpret_cast<const float4*>(gamma_h + base + 4 * k);
        hh[4 * k + 0] = hv.x * gv.x;
        hh[4 * k + 1] = hv.y * gv.y;
        hh[4 * k + 2] = hv.z * gv.z;
        hh[4 * k + 3] = hv.w * gv.w;
    }

    const float xb = X[(long)b * I_TOT + i];
    const float mb = M[(long)b * I_TOT + i];

    // r and z pre-activations: init with X*W + M*V + bias, then += hh @ U
    float accr[D_DIM], accz[D_DIM];
    #pragma unroll
    for (int e = 0; e < D_DIM; ++e) {
        accr[e] = fmaf(xb, Wr[e], fmaf(mb, Vr[e], br[e]));
        accz[e] = fmaf(xb, Wz[e], fmaf(mb, Vz[e], bz[e]));
    }
    #pragma unroll
    for (int d = 0; d < D_DIM; ++d) {
        const float hd = hh[d];
        #pragma unroll
        for (int e = 0; e < D_DIM; ++e) {
            accr[e] = fmaf(hd, Ur[d * D_DIM + e], accr[e]);
            accz[e] = fmaf(hd, Uz[d * D_DIM + e], accz[e]);
        }
    }

    // gates; rhh = r * hh
    float z[D_DIM], rhh[D_DIM];
    #pragma unroll
    for (int e = 0; e < D_DIM; ++e) {
        float r = fast_sigmoid(accr[e]);
        z[e] = fast_sigmoid(accz[e]);
        rhh[e] = r * hh[e];
    }

    // h_tilde pre-activation
    float acch[D_DIM];
    #pragma unroll
    for (int e = 0; e < D_DIM; ++e) {
        acch[e] = fmaf(xb, Wh[e], fmaf(mb, Vh[e], bh[e]));
    }
    #pragma unroll
    for (int d = 0; d < D_DIM; ++d) {
        const float rd = rhh[d];
        #pragma unroll
        for (int e = 0; e < D_DIM; ++e) {
            acch[e] = fmaf(rd, Uh[d * D_DIM + e], acch[e]);
        }
    }

    // out = z * hh + (1 - z) * tanh(acch)
    #pragma unroll
    for (int k = 0; k < 4; ++k) {
        float4 o;
        {
            float ht = fast_tanh(acch[4 * k + 0]);
            o.x = fmaf(z[4 * k + 0], hh[4 * k + 0] - ht, ht);
            ht = fast_tanh(acch[4 * k + 1]);
            o.y = fmaf(z[4 * k + 1], hh[4 * k + 1] - ht, ht);
            ht = fast_tanh(acch[4 * k + 2]);
            o.z = fmaf(z[4 * k + 2], hh[4 * k + 2] - ht, ht);
            ht = fast_tanh(acch[4 * k + 3]);
            o.w = fmaf(z[4 * k + 3], hh[4 * k + 3] - ht, ht);
        }
        *reinterpret_cast<float4*>(out + base + 4 * k) = o;
    }
}

extern "C" void kernel_launch(void* const* d_in, const int* in_sizes, int n_in,
                              void* d_out, int out_size, void* d_ws, size_t ws_size,
                              hipStream_t stream) {
    const float* h       = (const float*)d_in[0];
    const float* X       = (const float*)d_in[1];
    const float* M       = (const float*)d_in[2];
    const float* gamma_h = (const float*)d_in[3];
    const float* W_r     = (const float*)d_in[4];
    const float* W_z     = (const float*)d_in[5];
    const float* W_h     = (const float*)d_in[6];
    const float* U_r     = (const float*)d_in[7];
    const float* U_z     = (const float*)d_in[8];
    const float* U_h     = (const float*)d_in[9];
    const float* V_r     = (const float*)d_in[10];
    const float* V_z     = (const float*)d_in[11];
    const float* V_h     = (const float*)d_in[12];
    const float* b_r     = (const float*)d_in[13];
    const float* b_z     = (const float*)d_in[14];
    const float* b_h     = (const float*)d_in[15];
    float* out = (float*)d_out;

    const int B = 16384;
    dim3 grid(B / 256, I_TOT);   // (64, 128)
    dim3 block(256);
    gru_d_cell<<<grid, block, 0, stream>>>(h, X, M, gamma_h,
                                           W_r, W_z, W_h,
                                           U_r, U_z, U_h,
                                           V_r, V_z, V_h,
                                           b_r, b_z, b_h,
                                           out);
}

// Round 2
// 157.796 us; speedup vs baseline: 1.0942x; 1.0942x over previous
//
#include <hip/hip_runtime.h>
#include <hip/hip_bf16.h>

// GRU-D cell: B=16384, I=128, D=16.
// One thread per (b, i) block. Phased to keep peak live floats ~48:
//   hh -> accr -> rhh (accr dies) -> acch (rhh dies) -> accz -> out.
// U matrices indexed by wave-uniform blockIdx.y -> scalarized s_loads.
// __launch_bounds__(256,2) lifts the VGPR cap so nothing spills to scratch.

constexpr int I_TOT = 128;
constexpr int D_DIM = 16;

__device__ __forceinline__ float fast_sigmoid(float x) {
    float e = __expf(-x);                       // v_exp_f32
    return __builtin_amdgcn_rcpf(1.0f + e);     // v_rcp_f32 (approx, plenty for 9.75e-2 tol)
}

__device__ __forceinline__ float fast_tanh(float x) {
    x = fminf(fmaxf(x, -10.0f), 10.0f);
    float e = __expf(-2.0f * x);
    return (1.0f - e) * __builtin_amdgcn_rcpf(1.0f + e);
}

__global__ __launch_bounds__(256, 2) void gru_d_cell(
    const float* __restrict__ h,
    const float* __restrict__ X,
    const float* __restrict__ M,
    const float* __restrict__ gamma_h,
    const float* __restrict__ W_r,
    const float* __restrict__ W_z,
    const float* __restrict__ W_h,
    const float* __restrict__ U_r,
    const float* __restrict__ U_z,
    const float* __restrict__ U_h,
    const float* __restrict__ V_r,
    const float* __restrict__ V_z,
    const float* __restrict__ V_h,
    const float* __restrict__ b_r,
    const float* __restrict__ b_z,
    const float* __restrict__ b_h,
    float* __restrict__ out)
{
    const int i = blockIdx.y;                        // wave-uniform feature index
    const int b = blockIdx.x * 256 + threadIdx.x;    // batch index

    // Wave-uniform parameter bases -> scalar (SGPR) loads.
    const float* __restrict__ Ur = U_r + i * (D_DIM * D_DIM);
    const float* __restrict__ Uz = U_z + i * (D_DIM * D_DIM);
    const float* __restrict__ Uh = U_h + i * (D_DIM * D_DIM);
    const float* __restrict__ Wr = W_r + i * D_DIM;
    const float* __restrict__ Wz = W_z + i * D_DIM;
    const float* __restrict__ Wh = W_h + i * D_DIM;
    const float* __restrict__ Vr = V_r + i * D_DIM;
    const float* __restrict__ Vz = V_z + i * D_DIM;
    const float* __restrict__ Vh = V_h + i * D_DIM;
    const float* __restrict__ br = b_r + i * D_DIM;
    const float* __restrict__ bz = b_z + i * D_DIM;
    const float* __restrict__ bh = b_h + i * D_DIM;

    const size_t base = (size_t)b * (I_TOT * D_DIM) + (size_t)i * D_DIM;

    // hh = h * gamma_h
    float hh[D_DIM];
    #pragma unroll
    for (int k = 0; k < 4; ++k) {
        float4 hv = *reinterpret_cast<const float4*>(h + base + 4 * k);
        float4 gv = *reinterpret_cast<const float4*>(gamma_h + base + 4 * k);
        hh[4 * k + 0] = hv.x * gv.x;
        hh[4 * k + 1] = hv.y * gv.y;
        hh[4 * k + 2] = hv.z * gv.z;
        hh[4 * k + 3] = hv.w * gv.w;
    }

    const float xb = X[(size_t)b * I_TOT + i];
    const float mb = M[(size_t)b * I_TOT + i];

    // Phase 1: accr = x*Wr + m*Vr + br + hh @ Ur        (live: hh, accr = 32)
    float accr[D_DIM];
    #pragma unroll
    for (int e = 0; e < D_DIM; ++e)
        accr[e] = fmaf(xb, Wr[e], fmaf(mb, Vr[e], br[e]));
    #pragma unroll
    for (int d = 0; d < D_DIM; ++d) {
        const float hd = hh[d];
        #pragma unroll
        for (int e = 0; e < D_DIM; ++e)
            accr[e] = fmaf(hd, Ur[d * D_DIM + e], accr[e]);
    }

    // rhh = sigmoid(accr) * hh   (accr dies; live: hh, rhh = 32)
    float rhh[D_DIM];
    #pragma unroll
    for (int e = 0; e < D_DIM; ++e)
        rhh[e] = fast_sigmoid(accr[e]) * hh[e];

    // Phase 2: acch = x*Wh + m*Vh + bh + rhh @ Uh       (live: hh, rhh, acch = 48)
    float acch[D_DIM];
    #pragma unroll
    for (int e = 0; e < D_DIM; ++e)
        acch[e] = fmaf(xb, Wh[e], fmaf(mb, Vh[e], bh[e]));
    #pragma unroll
    for (int d = 0; d < D_DIM; ++d) {
        const float rd = rhh[d];
        #pragma unroll
        for (int e = 0; e < D_DIM; ++e)
            acch[e] = fmaf(rd, Uh[d * D_DIM + e], acch[e]);
    }
    // rhh dies here.

    // Phase 3: accz = x*Wz + m*Vz + bz + hh @ Uz        (live: hh, acch, accz = 48)
    float accz[D_DIM];
    #pragma unroll
    for (int e = 0; e < D_DIM; ++e)
        accz[e] = fmaf(xb, Wz[e], fmaf(mb, Vz[e], bz[e]));
    #pragma unroll
    for (int d = 0; d < D_DIM; ++d) {
        const float hd = hh[d];
        #pragma unroll
        for (int e = 0; e < D_DIM; ++e)
            accz[e] = fmaf(hd, Uz[d * D_DIM + e], accz[e]);
    }

    // out = z * hh + (1 - z) * tanh(acch)
    #pragma unroll
    for (int k = 0; k < 4; ++k) {
        float4 o;
        {
            float zt = fast_sigmoid(accz[4 * k + 0]);
            float ht = fast_tanh(acch[4 * k + 0]);
            o.x = fmaf(zt, hh[4 * k + 0] - ht, ht);
            zt = fast_sigmoid(accz[4 * k + 1]);
            ht = fast_tanh(acch[4 * k + 1]);
            o.y = fmaf(zt, hh[4 * k + 1] - ht, ht);
            zt = fast_sigmoid(accz[4 * k + 2]);
            ht = fast_tanh(acch[4 * k + 2]);
            o.z = fmaf(zt, hh[4 * k + 2] - ht, ht);
            zt = fast_sigmoid(accz[4 * k + 3]);
            ht = fast_tanh(acch[4 * k + 3]);
            o.w = fmaf(zt, hh[4 * k + 3] - ht, ht);
        }
        *reinterpret_cast<float4*>(out + base + 4 * k) = o;
    }
}

extern "C" void kernel_launch(void* const* d_in, const int* in_sizes, int n_in,
                              void* d_out, int out_size, void* d_ws, size_t ws_size,
                              hipStream_t stream) {
    const float* h       = (const float*)d_in[0];
    const float* X       = (const float*)d_in[1];
    const float* M       = (const float*)d_in[2];
    const float* gamma_h = (const float*)d_in[3];
    const float* W_r     = (const float*)d_in[4];
    const float* W_z     = (const float*)d_in[5];
    const float* W_h     = (const float*)d_in[6];
    const float* U_r     = (const float*)d_in[7];
    const float* U_z     = (const float*)d_in[8];
    const float* U_h     = (const float*)d_in[9];
    const float* V_r     = (const float*)d_in[10];
    const float* V_z     = (const float*)d_in[11];
    const float* V_h     = (const float*)d_in[12];
    const float* b_r     = (const float*)d_in[13];
    const float* b_z     = (const float*)d_in[14];
    const float* b_h     = (const float*)d_in[15];
    float* out = (float*)d_out;

    const int B = 16384;
    dim3 grid(B / 256, I_TOT);   // (64, 128)
    dim3 block(256);
    gru_d_cell<<<grid, block, 0, stream>>>(h, X, M, gamma_h,
                                           W_r, W_z, W_h,
                                           U_r, U_z, U_h,
                                           V_r, V_z, V_h,
                                           b_r, b_z, b_h,
                                           out);
}

// Round 3
// 141.478 us; speedup vs baseline: 1.2204x; 1.1153x over previous
//
#include <hip/hip_runtime.h>
#include <hip/hip_bf16.h>

// GRU-D cell: B=16384, I=128, D=16.
// One thread per (b, i) block. i = blockIdx.y is block-uniform, so the three
// 16x16 U matrices + W/V/b vectors are staged in LDS once per block (3.6 KB)
// and read back as float4 same-address broadcasts (conflict-free, no VMEM,
// no SGPR-stream stalls). Phased liveness: hh -> accr -> rhh -> acch -> ht
// -> accz -> out keeps peak live floats ~48 so nothing spills.

constexpr int I_TOT = 128;
constexpr int D_DIM = 16;

__device__ __forceinline__ float fast_sigmoid(float x) {
    float e = __expf(-x);
    return __builtin_amdgcn_rcpf(1.0f + e);
}

__device__ __forceinline__ float fast_tanh(float x) {
    x = fminf(fmaxf(x, -10.0f), 10.0f);
    float e = __expf(-2.0f * x);
    return (1.0f - e) * __builtin_amdgcn_rcpf(1.0f + e);
}

__global__ __launch_bounds__(256) void gru_d_cell(
    const float* __restrict__ h,
    const float* __restrict__ X,
    const float* __restrict__ M,
    const float* __restrict__ gamma_h,
    const float* __restrict__ W_r,
    const float* __restrict__ W_z,
    const float* __restrict__ W_h,
    const float* __restrict__ U_r,
    const float* __restrict__ U_z,
    const float* __restrict__ U_h,
    const float* __restrict__ V_r,
    const float* __restrict__ V_z,
    const float* __restrict__ V_h,
    const float* __restrict__ b_r,
    const float* __restrict__ b_z,
    const float* __restrict__ b_h,
    float* __restrict__ out)
{
    __shared__ float sUr[256];
    __shared__ float sUz[256];
    __shared__ float sUh[256];
    __shared__ float sWr[16], sWz[16], sWh[16];
    __shared__ float sVr[16], sVz[16], sVh[16];
    __shared__ float sbr[16], sbz[16], sbh[16];

    const int i = blockIdx.y;        // block-uniform feature index
    const int t = threadIdx.x;

    // Stage parameters for this feature i into LDS (coalesced reads).
    sUr[t] = U_r[i * 256 + t];
    sUz[t] = U_z[i * 256 + t];
    sUh[t] = U_h[i * 256 + t];
    if (t < 16) {
        sWr[t] = W_r[i * 16 + t];
        sWz[t] = W_z[i * 16 + t];
        sWh[t] = W_h[i * 16 + t];
        sVr[t] = V_r[i * 16 + t];
        sVz[t] = V_z[i * 16 + t];
        sVh[t] = V_h[i * 16 + t];
        sbr[t] = b_r[i * 16 + t];
        sbz[t] = b_z[i * 16 + t];
        sbh[t] = b_h[i * 16 + t];
    }
    __syncthreads();

    const int b = blockIdx.x * 256 + t;
    const size_t base = ((size_t)b * I_TOT + i) * D_DIM;

    // hh = h * gamma_h
    float hh[D_DIM];
    #pragma unroll
    for (int k = 0; k < 4; ++k) {
        float4 hv = *reinterpret_cast<const float4*>(h + base + 4 * k);
        float4 gv = *reinterpret_cast<const float4*>(gamma_h + base + 4 * k);
        hh[4 * k + 0] = hv.x * gv.x;
        hh[4 * k + 1] = hv.y * gv.y;
        hh[4 * k + 2] = hv.z * gv.z;
        hh[4 * k + 3] = hv.w * gv.w;
    }

    const float xb = X[(size_t)b * I_TOT + i];
    const float mb = M[(size_t)b * I_TOT + i];

    // ---- Phase 1: accr = x*Wr + m*Vr + br + hh @ Ur   (live: hh, accr) ----
    float accr[D_DIM];
    #pragma unroll
    for (int k = 0; k < 4; ++k) {
        float4 w = *reinterpret_cast<const float4*>(&sWr[4 * k]);
        float4 v = *reinterpret_cast<const float4*>(&sVr[4 * k]);
        float4 bi = *reinterpret_cast<const float4*>(&sbr[4 * k]);
        accr[4 * k + 0] = fmaf(xb, w.x, fmaf(mb, v.x, bi.x));
        accr[4 * k + 1] = fmaf(xb, w.y, fmaf(mb, v.y, bi.y));
        accr[4 * k + 2] = fmaf(xb, w.z, fmaf(mb, v.z, bi.z));
        accr[4 * k + 3] = fmaf(xb, w.w, fmaf(mb, v.w, bi.w));
    }
    #pragma unroll
    for (int d = 0; d < D_DIM; ++d) {
        const float hd = hh[d];
        #pragma unroll
        for (int k = 0; k < 4; ++k) {
            float4 u = *reinterpret_cast<const float4*>(&sUr[d * D_DIM + 4 * k]);
            accr[4 * k + 0] = fmaf(hd, u.x, accr[4 * k + 0]);
            accr[4 * k + 1] = fmaf(hd, u.y, accr[4 * k + 1]);
            accr[4 * k + 2] = fmaf(hd, u.z, accr[4 * k + 2]);
            accr[4 * k + 3] = fmaf(hd, u.w, accr[4 * k + 3]);
        }
    }

    // rhh = sigmoid(accr) * hh    (accr dies)
    float rhh[D_DIM];
    #pragma unroll
    for (int e = 0; e < D_DIM; ++e)
        rhh[e] = fast_sigmoid(accr[e]) * hh[e];

    // ---- Phase 2: acch = x*Wh + m*Vh + bh + rhh @ Uh  (live: hh, rhh, acch) ----
    float acch[D_DIM];
    #pragma unroll
    for (int k = 0; k < 4; ++k) {
        float4 w = *reinterpret_cast<const float4*>(&sWh[4 * k]);
        float4 v = *reinterpret_cast<const float4*>(&sVh[4 * k]);
        float4 bi = *reinterpret_cast<const float4*>(&sbh[4 * k]);
        acch[4 * k + 0] = fmaf(xb, w.x, fmaf(mb, v.x, bi.x));
        acch[4 * k + 1] = fmaf(xb, w.y, fmaf(mb, v.y, bi.y));
        acch[4 * k + 2] = fmaf(xb, w.z, fmaf(mb, v.z, bi.z));
        acch[4 * k + 3] = fmaf(xb, w.w, fmaf(mb, v.w, bi.w));
    }
    #pragma unroll
    for (int d = 0; d < D_DIM; ++d) {
        const float rd = rhh[d];
        #pragma unroll
        for (int k = 0; k < 4; ++k) {
            float4 u = *reinterpret_cast<const float4*>(&sUh[d * D_DIM + 4 * k]);
            acch[4 * k + 0] = fmaf(rd, u.x, acch[4 * k + 0]);
            acch[4 * k + 1] = fmaf(rd, u.y, acch[4 * k + 1]);
            acch[4 * k + 2] = fmaf(rd, u.z, acch[4 * k + 2]);
            acch[4 * k + 3] = fmaf(rd, u.w, acch[4 * k + 3]);
        }
    }
    // rhh dies; ht = tanh(acch) overwrites acch's role
    float ht[D_DIM];
    #pragma unroll
    for (int e = 0; e < D_DIM; ++e)
        ht[e] = fast_tanh(acch[e]);

    // ---- Phase 3: accz = x*Wz + m*Vz + bz + hh @ Uz   (live: hh, ht, accz) ----
    float accz[D_DIM];
    #pragma unroll
    for (int k = 0; k < 4; ++k) {
        float4 w = *reinterpret_cast<const float4*>(&sWz[4 * k]);
        float4 v = *reinterpret_cast<const float4*>(&sVz[4 * k]);
        float4 bi = *reinterpret_cast<const float4*>(&sbz[4 * k]);
        accz[4 * k + 0] = fmaf(xb, w.x, fmaf(mb, v.x, bi.x));
        accz[4 * k + 1] = fmaf(xb, w.y, fmaf(mb, v.y, bi.y));
        accz[4 * k + 2] = fmaf(xb, w.z, fmaf(mb, v.z, bi.z));
        accz[4 * k + 3] = fmaf(xb, w.w, fmaf(mb, v.w, bi.w));
    }
    #pragma unroll
    for (int d = 0; d < D_DIM; ++d) {
        const float hd = hh[d];
        #pragma unroll
        for (int k = 0; k < 4; ++k) {
            float4 u = *reinterpret_cast<const float4*>(&sUz[d * D_DIM + 4 * k]);
            accz[4 * k + 0] = fmaf(hd, u.x, accz[4 * k + 0]);
            accz[4 * k + 1] = fmaf(hd, u.y, accz[4 * k + 1]);
            accz[4 * k + 2] = fmaf(hd, u.z, accz[4 * k + 2]);
            accz[4 * k + 3] = fmaf(hd, u.w, accz[4 * k + 3]);
        }
    }

    // out = z * hh + (1 - z) * ht
    #pragma unroll
    for (int k = 0; k < 4; ++k) {
        float4 o;
        float zt = fast_sigmoid(accz[4 * k + 0]);
        o.x = fmaf(zt, hh[4 * k + 0] - ht[4 * k + 0], ht[4 * k + 0]);
        zt = fast_sigmoid(accz[4 * k + 1]);
        o.y = fmaf(zt, hh[4 * k + 1] - ht[4 * k + 1], ht[4 * k + 1]);
        zt = fast_sigmoid(accz[4 * k + 2]);
        o.z = fmaf(zt, hh[4 * k + 2] - ht[4 * k + 2], ht[4 * k + 2]);
        zt = fast_sigmoid(accz[4 * k + 3]);
        o.w = fmaf(zt, hh[4 * k + 3] - ht[4 * k + 3], ht[4 * k + 3]);
        *reinterpret_cast<float4*>(out + base + 4 * k) = o;
    }
}

extern "C" void kernel_launch(void* const* d_in, const int* in_sizes, int n_in,
                              void* d_out, int out_size, void* d_ws, size_t ws_size,
                              hipStream_t stream) {
    const float* h       = (const float*)d_in[0];
    const float* X       = (const float*)d_in[1];
    const float* M       = (const float*)d_in[2];
    const float* gamma_h = (const float*)d_in[3];
    const float* W_r     = (const float*)d_in[4];
    const float* W_z     = (const float*)d_in[5];
    const float* W_h     = (const float*)d_in[6];
    const float* U_r     = (const float*)d_in[7];
    const float* U_z     = (const float*)d_in[8];
    const float* U_h     = (const float*)d_in[9];
    const float* V_r     = (const float*)d_in[10];
    const float* V_z     = (const float*)d_in[11];
    const float* V_h     = (const float*)d_in[12];
    const float* b_r     = (const float*)d_in[13];
    const float* b_z     = (const float*)d_in[14];
    const float* b_h     = (const float*)d_in[15];
    float* out = (float*)d_out;

    const int B = 16384;
    dim3 grid(B / 256, I_TOT);   // (64, 128)
    dim3 block(256);
    gru_d_cell<<<grid, block, 0, stream>>>(h, X, M, gamma_h,
                                           W_r, W_z, W_h,
                                           U_r, U_z, U_h,
                                           V_r, V_z, V_h,
                                           b_r, b_z, b_h,
                                           out);
}